// Round 1
// baseline (354.879 us; speedup 1.0000x reference)
//
#include <hip/hip_runtime.h>
#include <hip/hip_bf16.h>

// LocalFeatureAggregation: B=2, N=32768, K=16, CIN=8, COUT=64
// One thread per (point, k). Block = 256 = 16 points x 16 k. Grid = B*N/16 = 4096.

__global__ __launch_bounds__(256)
void lfa_kernel(const float* __restrict__ coords,   // (B,N,3)
                const float* __restrict__ feats,    // (B,N,8)
                const int*   __restrict__ nidx,     // (B,N,16)
                const float* __restrict__ w1, const float* __restrict__ g1, const float* __restrict__ b1,
                const float* __restrict__ w2, const float* __restrict__ g2, const float* __restrict__ b2,
                const float* __restrict__ wm1, const float* __restrict__ gm1, const float* __restrict__ bm1,
                const float* __restrict__ wm2, const float* __restrict__ gm2, const float* __restrict__ bm2,
                const float* __restrict__ watt,
                const float* __restrict__ wp, const float* __restrict__ gp, const float* __restrict__ bp,
                float* __restrict__ out)            // (B,N,64)
{
    const float BN_INV = 0.9999950000374997f;  // 1/sqrt(1+1e-5)

    __shared__ __align__(16) float sW1[8][4];
    __shared__ float sS1[8], sT1[8];
    __shared__ __align__(16) float sW2[16][8];
    __shared__ float sS2[16], sT2[16];
    __shared__ __align__(16) float sM1[32][24];
    __shared__ float sSM1[32], sTM1[32];
    __shared__ __align__(16) float sM2[64][32];
    __shared__ float sSM2[64], sTM2[64];
    __shared__ __align__(16) float sATT[64][64];
    __shared__ __align__(16) float sPWT[64][64];   // transposed pool weights: [c][o]
    __shared__ float sSP[64], sTP[64];

    const int tid = threadIdx.x;

    // ---- stage weights into LDS (fold BN scale) ----
    for (int i = tid; i < 32;   i += 256) ((float*)sW1)[i] = w1[i];
    for (int i = tid; i < 8;    i += 256) { sS1[i] = g1[i] * BN_INV; sT1[i] = b1[i]; }
    for (int i = tid; i < 128;  i += 256) ((float*)sW2)[i] = w2[i];
    for (int i = tid; i < 16;   i += 256) { sS2[i] = g2[i] * BN_INV; sT2[i] = b2[i]; }
    for (int i = tid; i < 768;  i += 256) ((float*)sM1)[i] = wm1[i];
    for (int i = tid; i < 32;   i += 256) { sSM1[i] = gm1[i] * BN_INV; sTM1[i] = bm1[i]; }
    for (int i = tid; i < 2048; i += 256) ((float*)sM2)[i] = wm2[i];
    for (int i = tid; i < 64;   i += 256) { sSM2[i] = gm2[i] * BN_INV; sTM2[i] = bm2[i]; }
    for (int i = tid; i < 4096; i += 256) ((float*)sATT)[i] = watt[i];
    for (int i = tid; i < 4096; i += 256) { int o = i >> 6, c = i & 63; sPWT[c][o] = wp[i]; }
    for (int i = tid; i < 64;   i += 256) { sSP[i] = gp[i] * BN_INV; sTP[i] = bp[i]; }
    __syncthreads();

    const int pt  = (blockIdx.x << 4) + (tid >> 4);  // global point id in [0, B*N)
    const int k   = tid & 15;                        // neighbor slot
    const int bb  = pt >> 15;                        // batch (N = 32768)
    const int nb  = nidx[pt * 16 + k];               // neighbor index within batch
    const int nbr = (bb << 15) + nb;                 // flat neighbor point id

    // ---- relative position encoding ----
    const float cx = coords[pt * 3 + 0], cy = coords[pt * 3 + 1], cz = coords[pt * 3 + 2];
    const float rx = coords[nbr * 3 + 0] - cx;
    const float ry = coords[nbr * 3 + 1] - cy;
    const float rz = coords[nbr * 3 + 2] - cz;
    const float dd = sqrtf(rx * rx + ry * ry + rz * rz);
    float e4[4] = {rx, ry, rz, dd};

    // ---- neighbor features (8 f32 = two float4, 16B-aligned) ----
    float nf[8];
    {
        const float4* fp4 = (const float4*)(feats + nbr * 8);
        float4 f0 = fp4[0], f1 = fp4[1];
        nf[0] = f0.x; nf[1] = f0.y; nf[2] = f0.z; nf[3] = f0.w;
        nf[4] = f1.x; nf[5] = f1.y; nf[6] = f1.z; nf[7] = f1.w;
    }

    // ---- LSE layer 1: 4 -> 8 ----
    float h1[8];
    #pragma unroll
    for (int o = 0; o < 8; ++o) {
        float a = 0.f;
        #pragma unroll
        for (int i = 0; i < 4; ++i) a = fmaf(sW1[o][i], e4[i], a);
        h1[o] = fmaxf(fmaf(a, sS1[o], sT1[o]), 0.f);
    }

    // ---- LSE layer 2: 8 -> 16, concat with nf -> x24 ----
    float x24[24];
    #pragma unroll
    for (int i = 0; i < 8; ++i) x24[i] = nf[i];
    #pragma unroll
    for (int o = 0; o < 16; ++o) {
        float a = 0.f;
        #pragma unroll
        for (int i = 0; i < 8; ++i) a = fmaf(sW2[o][i], h1[i], a);
        x24[8 + o] = fmaxf(fmaf(a, sS2[o], sT2[o]), 0.f);
    }

    // ---- MLP1: 24 -> 32 ----
    float a1[32];
    #pragma unroll
    for (int o = 0; o < 32; ++o) {
        float a = 0.f;
        #pragma unroll
        for (int i = 0; i < 24; ++i) a = fmaf(sM1[o][i], x24[i], a);
        a1[o] = fmaxf(fmaf(a, sSM1[o], sTM1[o]), 0.f);
    }

    // ---- MLP2: 32 -> 64 ----
    float xv[64];
    #pragma unroll
    for (int o = 0; o < 64; ++o) {
        float a = 0.f;
        #pragma unroll
        for (int i = 0; i < 32; ++i) a = fmaf(sM2[o][i], a1[i], a);
        xv[o] = fmaxf(fmaf(a, sSM2[o], sTM2[o]), 0.f);
    }

    // ---- attentive pooling fused with final 64->64 layer ----
    // scores = softmax_k(xv @ att^T); pooled_c = sum_k e_kc * x_kc / sum_k e_kc
    // acc_o += pooled_c * pool_w[o][c] accumulated channel-by-channel.
    float acc0 = 0.f, acc1 = 0.f, acc2 = 0.f, acc3 = 0.f;
    const int ob = k << 2;   // this lane owns output channels ob..ob+3
    #pragma unroll
    for (int c = 0; c < 64; ++c) {
        float s = 0.f;
        #pragma unroll
        for (int i = 0; i < 64; ++i) s = fmaf(sATT[c][i], xv[i], s);
        float e   = __expf(s);
        float num = e * xv[c];
        // 16-lane (one point) butterfly reduction of (num, e)
        #pragma unroll
        for (int m = 1; m < 16; m <<= 1) {
            e   += __shfl_xor(e,   m, 64);
            num += __shfl_xor(num, m, 64);
        }
        const float pooled = __fdividef(num, e);
        const float4 pw = *(const float4*)&sPWT[c][ob];
        acc0 = fmaf(pooled, pw.x, acc0);
        acc1 = fmaf(pooled, pw.y, acc1);
        acc2 = fmaf(pooled, pw.z, acc2);
        acc3 = fmaf(pooled, pw.w, acc3);
    }

    float4 r;
    r.x = fmaxf(fmaf(acc0, sSP[ob + 0], sTP[ob + 0]), 0.f);
    r.y = fmaxf(fmaf(acc1, sSP[ob + 1], sTP[ob + 1]), 0.f);
    r.z = fmaxf(fmaf(acc2, sSP[ob + 2], sTP[ob + 2]), 0.f);
    r.w = fmaxf(fmaf(acc3, sSP[ob + 3], sTP[ob + 3]), 0.f);
    *(float4*)(out + pt * 64 + ob) = r;
}

extern "C" void kernel_launch(void* const* d_in, const int* in_sizes, int n_in,
                              void* d_out, int out_size, void* d_ws, size_t ws_size,
                              hipStream_t stream) {
    (void)in_sizes; (void)n_in; (void)d_ws; (void)ws_size; (void)out_size;
    const float* coords = (const float*)d_in[0];
    const float* feats  = (const float*)d_in[1];
    const int*   nidx   = (const int*)  d_in[2];
    const float* w1  = (const float*)d_in[3];
    const float* g1  = (const float*)d_in[4];
    const float* b1  = (const float*)d_in[5];
    const float* w2  = (const float*)d_in[6];
    const float* g2  = (const float*)d_in[7];
    const float* b2  = (const float*)d_in[8];
    const float* wm1 = (const float*)d_in[9];
    const float* gm1 = (const float*)d_in[10];
    const float* bm1 = (const float*)d_in[11];
    const float* wm2 = (const float*)d_in[12];
    const float* gm2 = (const float*)d_in[13];
    const float* bm2 = (const float*)d_in[14];
    const float* watt = (const float*)d_in[15];
    const float* wp  = (const float*)d_in[16];
    const float* gp  = (const float*)d_in[17];
    const float* bp  = (const float*)d_in[18];
    float* out = (float*)d_out;

    // B*N = 65536 points, 16 points per block
    dim3 grid(4096), block(256);
    lfa_kernel<<<grid, block, 0, stream>>>(coords, feats, nidx,
                                           w1, g1, b1, w2, g2, b2,
                                           wm1, gm1, bm1, wm2, gm2, bm2,
                                           watt, wp, gp, bp, out);
}

// Round 2
// 270.663 us; speedup vs baseline: 1.3111x; 1.3111x over previous
//
#include <hip/hip_runtime.h>
#include <hip/hip_bf16.h>

// LocalFeatureAggregation: B=2, N=32768, K=16, CIN=8, COUT=64
// One thread per (point, k). Block = 256 = 16 points x 16 k. Grid = B*N/16 = 4096.
// All weight reads are wave-uniform -> scalar pipe (s_load). Only lane-indexed
// pool weights (transposed) + pool scale/shift live in LDS.

__global__ __launch_bounds__(256, 3)
void lfa_kernel(const float* __restrict__ coords,   // (B,N,3)
                const float* __restrict__ feats,    // (B,N,8)
                const int*   __restrict__ nidx,     // (B,N,16)
                const float* __restrict__ w1, const float* __restrict__ g1, const float* __restrict__ b1,
                const float* __restrict__ w2, const float* __restrict__ g2, const float* __restrict__ b2,
                const float* __restrict__ wm1, const float* __restrict__ gm1, const float* __restrict__ bm1,
                const float* __restrict__ wm2, const float* __restrict__ gm2, const float* __restrict__ bm2,
                const float* __restrict__ watt,
                const float* __restrict__ wp, const float* __restrict__ gp, const float* __restrict__ bp,
                float* __restrict__ out)            // (B,N,64)
{
    const float BN_INV = 0.9999950000374997f;  // 1/sqrt(1+1e-5)

    __shared__ __align__(16) float sPWT[64][64];   // transposed pool weights: [c][o]
    __shared__ float sSP[64], sTP[64];

    const int tid = threadIdx.x;

    for (int i = tid; i < 4096; i += 256) { int o = i >> 6, c = i & 63; sPWT[c][o] = wp[i]; }
    for (int i = tid; i < 64;   i += 256) { sSP[i] = gp[i] * BN_INV; sTP[i] = bp[i]; }
    __syncthreads();

    const int pt  = (blockIdx.x << 4) + (tid >> 4);  // global point id in [0, B*N)
    const int k   = tid & 15;                        // neighbor slot
    const int bb  = pt >> 15;                        // batch (N = 32768)
    const int nb  = nidx[pt * 16 + k];               // neighbor index within batch
    const int nbr = (bb << 15) + nb;                 // flat neighbor point id

    // ---- relative position encoding ----
    const float cx = coords[pt * 3 + 0], cy = coords[pt * 3 + 1], cz = coords[pt * 3 + 2];
    const float rx = coords[nbr * 3 + 0] - cx;
    const float ry = coords[nbr * 3 + 1] - cy;
    const float rz = coords[nbr * 3 + 2] - cz;
    const float dd = sqrtf(rx * rx + ry * ry + rz * rz);
    float e4[4] = {rx, ry, rz, dd};

    // ---- neighbor features (8 f32 = two float4, 16B-aligned) ----
    float nf[8];
    {
        const float4* fp4 = (const float4*)(feats + nbr * 8);
        float4 f0 = fp4[0], f1 = fp4[1];
        nf[0] = f0.x; nf[1] = f0.y; nf[2] = f0.z; nf[3] = f0.w;
        nf[4] = f1.x; nf[5] = f1.y; nf[6] = f1.z; nf[7] = f1.w;
    }

    // ---- LSE layer 1: 4 -> 8  (weights via scalar loads) ----
    float h1[8];
    #pragma unroll
    for (int o = 0; o < 8; ++o) {
        float a = 0.f;
        #pragma unroll
        for (int i = 0; i < 4; ++i) a = fmaf(w1[o * 4 + i], e4[i], a);
        h1[o] = fmaxf(fmaf(a, g1[o] * BN_INV, b1[o]), 0.f);
    }

    // ---- LSE layer 2: 8 -> 16, concat with nf -> x24 ----
    float x24[24];
    #pragma unroll
    for (int i = 0; i < 8; ++i) x24[i] = nf[i];
    #pragma unroll
    for (int o = 0; o < 16; ++o) {
        float a = 0.f;
        #pragma unroll
        for (int i = 0; i < 8; ++i) a = fmaf(w2[o * 8 + i], h1[i], a);
        x24[8 + o] = fmaxf(fmaf(a, g2[o] * BN_INV, b2[o]), 0.f);
    }

    // ---- MLP1: 24 -> 32 ----
    float a1[32];
    #pragma unroll
    for (int o = 0; o < 32; ++o) {
        float a = 0.f;
        #pragma unroll
        for (int i = 0; i < 24; ++i) a = fmaf(wm1[o * 24 + i], x24[i], a);
        a1[o] = fmaxf(fmaf(a, gm1[o] * BN_INV, bm1[o]), 0.f);
    }

    // ---- MLP2: 32 -> 64 ----
    float xv[64];
    #pragma unroll
    for (int o = 0; o < 64; ++o) {
        float a = 0.f;
        #pragma unroll
        for (int i = 0; i < 32; ++i) a = fmaf(wm2[o * 32 + i], a1[i], a);
        xv[o] = fmaxf(fmaf(a, gm2[o] * BN_INV, bm2[o]), 0.f);
    }

    // ---- attentive pooling fused with final 64->64 layer ----
    float acc0 = 0.f, acc1 = 0.f, acc2 = 0.f, acc3 = 0.f;
    const int ob = k << 2;   // this lane owns output channels ob..ob+3
    #pragma unroll
    for (int c = 0; c < 64; ++c) {
        float s = 0.f;
        #pragma unroll
        for (int i = 0; i < 64; ++i) s = fmaf(watt[c * 64 + i], xv[i], s);
        float e   = __expf(s);
        float num = e * xv[c];
        // 16-lane (one point) butterfly reduction of (num, e)
        #pragma unroll
        for (int m = 1; m < 16; m <<= 1) {
            e   += __shfl_xor(e,   m, 64);
            num += __shfl_xor(num, m, 64);
        }
        const float pooled = __fdividef(num, e);
        const float4 pw = *(const float4*)&sPWT[c][ob];
        acc0 = fmaf(pooled, pw.x, acc0);
        acc1 = fmaf(pooled, pw.y, acc1);
        acc2 = fmaf(pooled, pw.z, acc2);
        acc3 = fmaf(pooled, pw.w, acc3);
    }

    float4 r;
    r.x = fmaxf(fmaf(acc0, sSP[ob + 0], sTP[ob + 0]), 0.f);
    r.y = fmaxf(fmaf(acc1, sSP[ob + 1], sTP[ob + 1]), 0.f);
    r.z = fmaxf(fmaf(acc2, sSP[ob + 2], sTP[ob + 2]), 0.f);
    r.w = fmaxf(fmaf(acc3, sSP[ob + 3], sTP[ob + 3]), 0.f);
    *(float4*)(out + pt * 64 + ob) = r;
}

extern "C" void kernel_launch(void* const* d_in, const int* in_sizes, int n_in,
                              void* d_out, int out_size, void* d_ws, size_t ws_size,
                              hipStream_t stream) {
    (void)in_sizes; (void)n_in; (void)d_ws; (void)ws_size; (void)out_size;
    const float* coords = (const float*)d_in[0];
    const float* feats  = (const float*)d_in[1];
    const int*   nidx   = (const int*)  d_in[2];
    const float* w1  = (const float*)d_in[3];
    const float* g1  = (const float*)d_in[4];
    const float* b1  = (const float*)d_in[5];
    const float* w2  = (const float*)d_in[6];
    const float* g2  = (const float*)d_in[7];
    const float* b2  = (const float*)d_in[8];
    const float* wm1 = (const float*)d_in[9];
    const float* gm1 = (const float*)d_in[10];
    const float* bm1 = (const float*)d_in[11];
    const float* wm2 = (const float*)d_in[12];
    const float* gm2 = (const float*)d_in[13];
    const float* bm2 = (const float*)d_in[14];
    const float* watt = (const float*)d_in[15];
    const float* wp  = (const float*)d_in[16];
    const float* gp  = (const float*)d_in[17];
    const float* bp  = (const float*)d_in[18];
    float* out = (float*)d_out;

    dim3 grid(4096), block(256);
    lfa_kernel<<<grid, block, 0, stream>>>(coords, feats, nidx,
                                           w1, g1, b1, w2, g2, b2,
                                           wm1, gm1, bm1, wm2, gm2, bm2,
                                           watt, wp, gp, bp, out);
}

// Round 3
// 219.675 us; speedup vs baseline: 1.6155x; 1.2321x over previous
//
#include <hip/hip_runtime.h>
#include <hip/hip_bf16.h>

// LocalFeatureAggregation: B=2, N=32768, K=16, CIN=8, COUT=64
// One thread per (point, k). Block = 256 = 16 points x 16 k. Grid = 4096.
// Weights via scalar (s_load) path; softmax reduction via DPP (no LDS);
// launch_bounds(256,2) -> 256-VGPR budget so xv[64] stays in arch VGPRs.

template <int CTRL>
__device__ __forceinline__ float dpp_add(float v) {
    int t = __builtin_amdgcn_update_dpp(0, __float_as_int(v), CTRL, 0xF, 0xF, true);
    return v + __int_as_float(t);
}

// reduce (sum) across the 16-lane group; every lane ends with the total
__device__ __forceinline__ float row16_sum(float v) {
    v = dpp_add<0xB1>(v);   // quad_perm(1,0,3,2)  : xor 1
    v = dpp_add<0x4E>(v);   // quad_perm(2,3,0,1)  : xor 2
    v = dpp_add<0x124>(v);  // row_ror:4           : + next quad
    v = dpp_add<0x128>(v);  // row_ror:8           : + other half
    return v;
}

__global__ __launch_bounds__(256, 2)
void lfa_kernel(const float* __restrict__ coords,   // (B,N,3)
                const float* __restrict__ feats,    // (B,N,8)
                const int*   __restrict__ nidx,     // (B,N,16)
                const float* __restrict__ w1, const float* __restrict__ g1, const float* __restrict__ b1,
                const float* __restrict__ w2, const float* __restrict__ g2, const float* __restrict__ b2,
                const float* __restrict__ wm1, const float* __restrict__ gm1, const float* __restrict__ bm1,
                const float* __restrict__ wm2, const float* __restrict__ gm2, const float* __restrict__ bm2,
                const float* __restrict__ watt,
                const float* __restrict__ wp, const float* __restrict__ gp, const float* __restrict__ bp,
                float* __restrict__ out)            // (B,N,64)
{
    const float BN_INV = 0.9999950000374997f;  // 1/sqrt(1+1e-5)

    __shared__ __align__(16) float sPWT[64][64];   // transposed pool weights: [c][o]
    __shared__ float sSP[64], sTP[64];

    const int tid = threadIdx.x;

    for (int i = tid; i < 4096; i += 256) { int o = i >> 6, c = i & 63; sPWT[c][o] = wp[i]; }
    for (int i = tid; i < 64;   i += 256) { sSP[i] = gp[i] * BN_INV; sTP[i] = bp[i]; }
    __syncthreads();

    const int pt  = (blockIdx.x << 4) + (tid >> 4);  // global point id in [0, B*N)
    const int k   = tid & 15;                        // neighbor slot
    const int bb  = pt >> 15;                        // batch (N = 32768)
    const int nb  = nidx[pt * 16 + k];               // neighbor index within batch
    const int nbr = (bb << 15) + nb;                 // flat neighbor point id

    // ---- relative position encoding ----
    const float cx = coords[pt * 3 + 0], cy = coords[pt * 3 + 1], cz = coords[pt * 3 + 2];
    const float rx = coords[nbr * 3 + 0] - cx;
    const float ry = coords[nbr * 3 + 1] - cy;
    const float rz = coords[nbr * 3 + 2] - cz;
    const float dd = sqrtf(rx * rx + ry * ry + rz * rz);
    float e4[4] = {rx, ry, rz, dd};

    // ---- neighbor features ----
    float nf[8];
    {
        const float4* fp4 = (const float4*)(feats + nbr * 8);
        float4 f0 = fp4[0], f1 = fp4[1];
        nf[0] = f0.x; nf[1] = f0.y; nf[2] = f0.z; nf[3] = f0.w;
        nf[4] = f1.x; nf[5] = f1.y; nf[6] = f1.z; nf[7] = f1.w;
    }

    // ---- LSE layer 1: 4 -> 8 ----
    float h1[8];
    #pragma unroll
    for (int o = 0; o < 8; ++o) {
        float a = 0.f;
        #pragma unroll
        for (int i = 0; i < 4; ++i) a = fmaf(w1[o * 4 + i], e4[i], a);
        h1[o] = fmaxf(fmaf(a, g1[o] * BN_INV, b1[o]), 0.f);
    }

    // ---- LSE layer 2: 8 -> 16, concat with nf -> x24 ----
    float x24[24];
    #pragma unroll
    for (int i = 0; i < 8; ++i) x24[i] = nf[i];
    #pragma unroll
    for (int o = 0; o < 16; ++o) {
        float a = 0.f;
        #pragma unroll
        for (int i = 0; i < 8; ++i) a = fmaf(w2[o * 8 + i], h1[i], a);
        x24[8 + o] = fmaxf(fmaf(a, g2[o] * BN_INV, b2[o]), 0.f);
    }

    // ---- MLP1: 24 -> 32 ----
    float a1[32];
    #pragma unroll
    for (int o = 0; o < 32; ++o) {
        float a = 0.f, b = 0.f;
        #pragma unroll
        for (int i = 0; i < 24; i += 2) {
            a = fmaf(wm1[o * 24 + i],     x24[i],     a);
            b = fmaf(wm1[o * 24 + i + 1], x24[i + 1], b);
        }
        a1[o] = fmaxf(fmaf(a + b, gm1[o] * BN_INV, bm1[o]), 0.f);
    }

    // ---- MLP2: 32 -> 64 ----
    float xv[64];
    #pragma unroll
    for (int o = 0; o < 64; ++o) {
        float a = 0.f, b = 0.f;
        #pragma unroll
        for (int i = 0; i < 32; i += 2) {
            a = fmaf(wm2[o * 32 + i],     a1[i],     a);
            b = fmaf(wm2[o * 32 + i + 1], a1[i + 1], b);
        }
        xv[o] = fmaxf(fmaf(a + b, gm2[o] * BN_INV, bm2[o]), 0.f);
    }

    // ---- attentive pooling fused with final 64->64 layer ----
    float acc0 = 0.f, acc1 = 0.f, acc2 = 0.f, acc3 = 0.f;
    const int ob = k << 2;   // this lane owns output channels ob..ob+3
    #pragma unroll
    for (int c = 0; c < 64; ++c) {
        float s0 = 0.f, s1 = 0.f, s2 = 0.f, s3 = 0.f;
        #pragma unroll
        for (int i = 0; i < 64; i += 4) {
            s0 = fmaf(watt[c * 64 + i],     xv[i],     s0);
            s1 = fmaf(watt[c * 64 + i + 1], xv[i + 1], s1);
            s2 = fmaf(watt[c * 64 + i + 2], xv[i + 2], s2);
            s3 = fmaf(watt[c * 64 + i + 3], xv[i + 3], s3);
        }
        const float s = (s0 + s1) + (s2 + s3);
        float e   = __expf(s);
        float num = e * xv[c];
        // 16-lane (one point) DPP sum of (num, e)
        e   = row16_sum(e);
        num = row16_sum(num);
        const float pooled = __fdividef(num, e);
        const float4 pw = *(const float4*)&sPWT[c][ob];
        acc0 = fmaf(pooled, pw.x, acc0);
        acc1 = fmaf(pooled, pw.y, acc1);
        acc2 = fmaf(pooled, pw.z, acc2);
        acc3 = fmaf(pooled, pw.w, acc3);
    }

    float4 r;
    r.x = fmaxf(fmaf(acc0, sSP[ob + 0], sTP[ob + 0]), 0.f);
    r.y = fmaxf(fmaf(acc1, sSP[ob + 1], sTP[ob + 1]), 0.f);
    r.z = fmaxf(fmaf(acc2, sSP[ob + 2], sTP[ob + 2]), 0.f);
    r.w = fmaxf(fmaf(acc3, sSP[ob + 3], sTP[ob + 3]), 0.f);
    *(float4*)(out + pt * 64 + ob) = r;
}

extern "C" void kernel_launch(void* const* d_in, const int* in_sizes, int n_in,
                              void* d_out, int out_size, void* d_ws, size_t ws_size,
                              hipStream_t stream) {
    (void)in_sizes; (void)n_in; (void)d_ws; (void)ws_size; (void)out_size;
    const float* coords = (const float*)d_in[0];
    const float* feats  = (const float*)d_in[1];
    const int*   nidx   = (const int*)  d_in[2];
    const float* w1  = (const float*)d_in[3];
    const float* g1  = (const float*)d_in[4];
    const float* b1  = (const float*)d_in[5];
    const float* w2  = (const float*)d_in[6];
    const float* g2  = (const float*)d_in[7];
    const float* b2  = (const float*)d_in[8];
    const float* wm1 = (const float*)d_in[9];
    const float* gm1 = (const float*)d_in[10];
    const float* bm1 = (const float*)d_in[11];
    const float* wm2 = (const float*)d_in[12];
    const float* gm2 = (const float*)d_in[13];
    const float* bm2 = (const float*)d_in[14];
    const float* watt = (const float*)d_in[15];
    const float* wp  = (const float*)d_in[16];
    const float* gp  = (const float*)d_in[17];
    const float* bp  = (const float*)d_in[18];
    float* out = (float*)d_out;

    dim3 grid(4096), block(256);
    lfa_kernel<<<grid, block, 0, stream>>>(coords, feats, nidx,
                                           w1, g1, b1, w2, g2, b2,
                                           wm1, gm1, bm1, wm2, gm2, bm2,
                                           watt, wp, gp, bp, out);
}

// Round 4
// 88.264 us; speedup vs baseline: 4.0206x; 2.4888x over previous
//
#include <hip/hip_runtime.h>
#include <hip/hip_bf16.h>

// LocalFeatureAggregation: B=2, N=32768, K=16, CIN=8, COUT=64
// MFMA version. Block = 256 = 4 waves. Each wave per iteration: LSE for 4
// points (64 lanes = 4pt x 16k), then per-point MFMA chain (16x16x32 bf16):
// MLP1 (2), MLP2 (4), ATT (8). Wave-local LDS bridges, no barriers.
// Grid = 512 blocks x 128 points each (8 iterations).

typedef __attribute__((ext_vector_type(8))) short short8v;
typedef __attribute__((ext_vector_type(4))) float float4v;

#define BN_INV 0.9999950000374997f

__device__ __forceinline__ ushort f2bf(float f) {
    __hip_bfloat16 h = __float2bfloat16(f);
    return __builtin_bit_cast(ushort, h);
}
__device__ __forceinline__ uint pk2(float a, float b) {
    return (uint)f2bf(a) | ((uint)f2bf(b) << 16);
}

__global__ __launch_bounds__(256, 2)
void lfa_kernel(const float* __restrict__ coords,
                const float* __restrict__ feats,
                const int*   __restrict__ nidx,
                const float* __restrict__ w1, const float* __restrict__ g1, const float* __restrict__ b1,
                const float* __restrict__ w2, const float* __restrict__ g2, const float* __restrict__ b2,
                const float* __restrict__ wm1, const float* __restrict__ gm1, const float* __restrict__ bm1,
                const float* __restrict__ wm2, const float* __restrict__ gm2, const float* __restrict__ bm2,
                const float* __restrict__ watt,
                const float* __restrict__ wp, const float* __restrict__ gp, const float* __restrict__ bp,
                float* __restrict__ out)
{
    // sX1: per wave 4 pts x 16 rows x 80B (row stride 40 ushorts, pt stride 648)
    // sX2: per wave 16 rows x 80B ; sX3: per wave 16 rows x 144B (72 ushorts)
    __shared__ __align__(16) float  sPWT[64][64];     // pool weights transposed [c][o]
    __shared__ __align__(16) ushort sX1[4 * 2592];
    __shared__ __align__(16) ushort sX2[4 * 640];
    __shared__ __align__(16) ushort sX3[4 * 1152];
    __shared__ __align__(16) float  sPool[4 * 64];

    const int tid = threadIdx.x;
    const int wv  = tid >> 6;
    const int l   = tid & 63;
    const int r   = l & 15;
    const int Q   = l >> 4;

    for (int i = tid; i < 4096; i += 256) { int o = i >> 6, c = i & 63; sPWT[c][o] = wp[i]; }
    __syncthreads();

    // ---- B fragments in registers (canonical: lane holds col n, k = 8Q+j) ----
    short8v b1f0, b1f1;
    #pragma unroll
    for (int j = 0; j < 8; ++j) {
        int k = 8 * Q + j;
        b1f0[j] = (short)((k < 24) ? f2bf(wm1[r * 24 + k])        : (ushort)0);
        b1f1[j] = (short)((k < 24) ? f2bf(wm1[(16 + r) * 24 + k]) : (ushort)0);
    }
    short8v b2f[4];
    #pragma unroll
    for (int t = 0; t < 4; ++t)
        #pragma unroll
        for (int j = 0; j < 8; ++j)
            b2f[t][j] = (short)f2bf(wm2[(16 * t + r) * 32 + 8 * Q + j]);
    short8v b3f[8];   // [t*2+h]
    #pragma unroll
    for (int t = 0; t < 4; ++t)
        #pragma unroll
        for (int h = 0; h < 2; ++h)
            #pragma unroll
            for (int j = 0; j < 8; ++j)
                b3f[t * 2 + h][j] = (short)f2bf(watt[(16 * t + r) * 64 + 32 * h + 8 * Q + j]);

    const float sm1a = gm1[r] * BN_INV,      tm1a = bm1[r];
    const float sm1b = gm1[16 + r] * BN_INV, tm1b = bm1[16 + r];
    float sm2[4], tm2[4];
    #pragma unroll
    for (int t = 0; t < 4; ++t) { sm2[t] = gm2[16 * t + r] * BN_INV; tm2[t] = bm2[16 * t + r]; }
    const float spv = gp[l] * BN_INV, tpv = bp[l];

    ushort* X1 = &sX1[wv * 2592];
    ushort* X2 = &sX2[wv * 640];
    ushort* X3 = &sX3[wv * 1152];
    float*  PL = &sPool[wv * 64];

    for (int it = 0; it < 8; ++it) {
        const int pt0 = blockIdx.x * 128 + it * 16 + wv * 4;

        // ===== LSE phase: lane = (point p=Q, neighbor k=r) =====
        {
            const int pt  = pt0 + Q;
            const int bb  = pt >> 15;
            const int nb  = nidx[pt0 * 16 + l];        // == nidx[pt*16 + r]
            const int nbr = (bb << 15) + nb;

            const float cx = coords[pt * 3 + 0], cy = coords[pt * 3 + 1], cz = coords[pt * 3 + 2];
            const float rx = coords[nbr * 3 + 0] - cx;
            const float ry = coords[nbr * 3 + 1] - cy;
            const float rz = coords[nbr * 3 + 2] - cz;
            const float dd = sqrtf(rx * rx + ry * ry + rz * rz);
            float e4[4] = {rx, ry, rz, dd};

            float x24[24];
            {
                const float4* fp4 = (const float4*)(feats + nbr * 8);
                float4 f0 = fp4[0], f1 = fp4[1];
                x24[0] = f0.x; x24[1] = f0.y; x24[2] = f0.z; x24[3] = f0.w;
                x24[4] = f1.x; x24[5] = f1.y; x24[6] = f1.z; x24[7] = f1.w;
            }
            float h1[8];
            #pragma unroll
            for (int o = 0; o < 8; ++o) {
                float a = 0.f;
                #pragma unroll
                for (int i = 0; i < 4; ++i) a = fmaf(w1[o * 4 + i], e4[i], a);
                h1[o] = fmaxf(fmaf(a, g1[o] * BN_INV, b1[o]), 0.f);
            }
            #pragma unroll
            for (int o = 0; o < 16; ++o) {
                float a = 0.f;
                #pragma unroll
                for (int i = 0; i < 8; ++i) a = fmaf(w2[o * 8 + i], h1[i], a);
                x24[8 + o] = fmaxf(fmaf(a, g2[o] * BN_INV, b2[o]), 0.f);
            }
            uint4* row = (uint4*)&X1[Q * 648 + r * 40];
            row[0] = make_uint4(pk2(x24[0],  x24[1]),  pk2(x24[2],  x24[3]),
                                pk2(x24[4],  x24[5]),  pk2(x24[6],  x24[7]));
            row[1] = make_uint4(pk2(x24[8],  x24[9]),  pk2(x24[10], x24[11]),
                                pk2(x24[12], x24[13]), pk2(x24[14], x24[15]));
            row[2] = make_uint4(pk2(x24[16], x24[17]), pk2(x24[18], x24[19]),
                                pk2(x24[20], x24[21]), pk2(x24[22], x24[23]));
            row[3] = make_uint4(0u, 0u, 0u, 0u);      // zero-pad ch 24..31
        }

        // ===== per-point MFMA chain =====
        #pragma unroll 1
        for (int p2 = 0; p2 < 4; ++p2) {
            const short8v a1 = *(const short8v*)&X1[p2 * 648 + r * 40 + Q * 8];
            float4v z0 = {0.f, 0.f, 0.f, 0.f};
            float4v d1a = __builtin_amdgcn_mfma_f32_16x16x32_bf16(a1, b1f0, z0, 0, 0, 0);
            float4v d1b = __builtin_amdgcn_mfma_f32_16x16x32_bf16(a1, b1f1, z0, 0, 0, 0);
            #pragma unroll
            for (int q = 0; q < 4; ++q) {
                float va = fmaxf(fmaf(d1a[q], sm1a, tm1a), 0.f);
                float vb = fmaxf(fmaf(d1b[q], sm1b, tm1b), 0.f);
                X2[(4 * Q + q) * 40 + r]      = f2bf(va);
                X2[(4 * Q + q) * 40 + 16 + r] = f2bf(vb);
            }
            const short8v a2 = *(const short8v*)&X2[r * 40 + Q * 8];
            float4v d2[4];
            #pragma unroll
            for (int t = 0; t < 4; ++t)
                d2[t] = __builtin_amdgcn_mfma_f32_16x16x32_bf16(a2, b2f[t], z0, 0, 0, 0);
            float xr[4][4];
            #pragma unroll
            for (int t = 0; t < 4; ++t)
                #pragma unroll
                for (int q = 0; q < 4; ++q) {
                    xr[t][q] = fmaxf(fmaf(d2[t][q], sm2[t], tm2[t]), 0.f);
                    X3[(4 * Q + q) * 72 + 16 * t + r] = f2bf(xr[t][q]);
                }
            const short8v a3l = *(const short8v*)&X3[r * 72 + Q * 8];
            const short8v a3h = *(const short8v*)&X3[r * 72 + 32 + Q * 8];
            float se[4], sn[4];
            #pragma unroll
            for (int t = 0; t < 4; ++t) {
                float4v s = __builtin_amdgcn_mfma_f32_16x16x32_bf16(a3l, b3f[t * 2],     z0, 0, 0, 0);
                s         = __builtin_amdgcn_mfma_f32_16x16x32_bf16(a3h, b3f[t * 2 + 1], s,  0, 0, 0);
                float e0 = __expf(s[0]), e1 = __expf(s[1]);
                float e2 = __expf(s[2]), e3 = __expf(s[3]);
                se[t] = (e0 + e1) + (e2 + e3);
                sn[t] = fmaf(e0, xr[t][0], e1 * xr[t][1]) + fmaf(e2, xr[t][2], e3 * xr[t][3]);
            }
            #pragma unroll
            for (int t = 0; t < 4; ++t) {
                se[t] += __shfl_xor(se[t], 16, 64);
                sn[t] += __shfl_xor(sn[t], 16, 64);
                se[t] += __shfl_xor(se[t], 32, 64);
                sn[t] += __shfl_xor(sn[t], 32, 64);
            }
            if (l < 16) {
                #pragma unroll
                for (int t = 0; t < 4; ++t)
                    PL[16 * t + l] = __fdividef(sn[t], se[t]);
            }
            float acc = 0.f;
            #pragma unroll
            for (int c = 0; c < 64; ++c) acc = fmaf(PL[c], sPWT[c][l], acc);
            out[(pt0 + p2) * 64 + l] = fmaxf(fmaf(acc, spv, tpv), 0.f);
        }
    }
}

extern "C" void kernel_launch(void* const* d_in, const int* in_sizes, int n_in,
                              void* d_out, int out_size, void* d_ws, size_t ws_size,
                              hipStream_t stream) {
    (void)in_sizes; (void)n_in; (void)d_ws; (void)ws_size; (void)out_size;
    const float* coords = (const float*)d_in[0];
    const float* feats  = (const float*)d_in[1];
    const int*   nidx   = (const int*)  d_in[2];
    const float* w1  = (const float*)d_in[3];
    const float* g1  = (const float*)d_in[4];
    const float* b1  = (const float*)d_in[5];
    const float* w2  = (const float*)d_in[6];
    const float* g2  = (const float*)d_in[7];
    const float* b2  = (const float*)d_in[8];
    const float* wm1 = (const float*)d_in[9];
    const float* gm1 = (const float*)d_in[10];
    const float* bm1 = (const float*)d_in[11];
    const float* wm2 = (const float*)d_in[12];
    const float* gm2 = (const float*)d_in[13];
    const float* bm2 = (const float*)d_in[14];
    const float* watt = (const float*)d_in[15];
    const float* wp  = (const float*)d_in[16];
    const float* gp  = (const float*)d_in[17];
    const float* bp  = (const float*)d_in[18];
    float* out = (float*)d_out;

    dim3 grid(512), block(256);
    lfa_kernel<<<grid, block, 0, stream>>>(coords, feats, nidx,
                                           w1, g1, b1, w2, g2, b2,
                                           wm1, gm1, bm1, wm2, gm2, bm2,
                                           watt, wp, gp, bp, out);
}